// Round 7
// baseline (215.866 us; speedup 1.0000x reference)
//
#include <hip/hip_runtime.h>
#include <hip/hip_fp16.h>

// B=4, Cin=64, Cout=128, H=W=128, 3x3, stride=1, pad=1, dil=1
#define HW    16384
#define NB    4
#define CIN   64
#define COUT  128

typedef short  short8  __attribute__((ext_vector_type(8)));
typedef _Float16 half8 __attribute__((ext_vector_type(8)));
typedef float  floatx4 __attribute__((ext_vector_type(4)));

__device__ __forceinline__ unsigned packh2(float a, float b) {
  __half2 h = __floats2half2_rn(a, b);
  return *(unsigned*)&h;
}
__device__ __forceinline__ short f2h(float f) {
  __half h = __float2half(f);
  return *(short*)&h;
}

// ---- packed-f16 bilinear helpers: broadcast one half of w via op_sel ----
__device__ __forceinline__ unsigned pk_mul_blo(unsigned a, unsigned w) {
  unsigned d;
  asm("v_pk_mul_f16 %0, %1, %2 op_sel:[0,0] op_sel_hi:[1,0]"
      : "=v"(d) : "v"(a), "v"(w));
  return d;
}
__device__ __forceinline__ unsigned pk_fma_blo(unsigned a, unsigned w, unsigned c) {
  unsigned d;
  asm("v_pk_fma_f16 %0, %1, %2, %3 op_sel:[0,0,0] op_sel_hi:[1,0,1]"
      : "=v"(d) : "v"(a), "v"(w), "v"(c));
  return d;
}
__device__ __forceinline__ unsigned pk_fma_bhi(unsigned a, unsigned w, unsigned c) {
  unsigned d;
  asm("v_pk_fma_f16 %0, %1, %2, %3 op_sel:[0,1,0] op_sel_hi:[1,1,1]"
      : "=v"(d) : "v"(a), "v"(w), "v"(c));
  return d;
}

// raw barriers (m201 pattern): lgkmcnt-only wait -> in-flight GLOBAL loads
// survive the barrier (syncthreads would drain vmcnt(0)).
#define BAR_W() { asm volatile("s_waitcnt lgkmcnt(0)" ::: "memory");  \
                  __builtin_amdgcn_s_barrier();                        \
                  __builtin_amdgcn_sched_barrier(0); }
#define BAR_R() { __builtin_amdgcn_s_barrier();                        \
                  __builtin_amdgcn_sched_barrier(0); }

// ---------------------------------------------------------------------------
// k_tr: CHW fp32 -> HWC f16 (xd=input_feat, xi=inter) + fused weight prep.
// ---------------------------------------------------------------------------
__global__ __launch_bounds__(256) void k_tr(const float* __restrict__ x,
                                            const float* __restrict__ inter,
                                            const float* __restrict__ weight,
                                            const float* __restrict__ w_om,
                                            short* __restrict__ xd,
                                            short* __restrict__ xi,
                                            short* __restrict__ wtbF,
                                            short* __restrict__ wtbomF) {
  __shared__ unsigned sT[64][69];
  const int blk = blockIdx.x;
  const int b = blk >> 8, hw0 = (blk & 255) * 64;
  const int tid = threadIdx.x;
  const int px = tid & 63, cg = tid >> 6;
  const float* s0 = x     + (size_t)b * CIN * HW + hw0 + px;
  const float* s1 = inter + (size_t)b * CIN * HW + hw0 + px;
#pragma unroll
  for (int step = 0; step < 16; ++step) {
    int cp = step * 4 + cg;
    int c = cp * 2;
    const float* s = (c < 64) ? (s0 + c * HW) : (s1 + (c - 64) * HW);
    sT[px][cp] = packh2(s[0], s[HW]);
  }
  {
    int i = blk * 256 + tid;
    if (i < 73728) {
      int i8 = i & 7, l = (i >> 3) & 15, q = (i >> 7) & 3;
      int t = (i >> 9) & 1, wv = (i >> 10) & 3, s = i >> 12;
      int o = wv * 32 + t * 16 + l;
      int k = s * 32 + q * 8 + i8;
      int c = k & 63, tap = k >> 6;
      wtbF[i] = f2h(weight[o * 576 + c * 9 + tap]);
    }
    if (i < 36864) {
      int i8 = i & 7, l = (i >> 3) & 15, q = (i >> 7) & 3;
      int t = (i >> 9) & 1, s = i >> 10;
      int o = t * 16 + l;
      int k = s * 32 + q * 8 + i8;
      int c = k & 127, tap = k >> 7;
      wtbomF[i] = (o < 27) ? f2h(w_om[o * 1152 + c * 9 + tap]) : (short)0;
    }
  }
  __syncthreads();
  const int od = tid & 7, p0 = tid >> 3;
#pragma unroll
  for (int it = 0; it < 2; ++it) {
    int p = p0 + it * 32;
    uint4 a, bvec;
    a.x = sT[p][od * 4 + 0]; a.y = sT[p][od * 4 + 1];
    a.z = sT[p][od * 4 + 2]; a.w = sT[p][od * 4 + 3];
    bvec.x = sT[p][32 + od * 4 + 0]; bvec.y = sT[p][32 + od * 4 + 1];
    bvec.z = sT[p][32 + od * 4 + 2]; bvec.w = sT[p][32 + od * 4 + 3];
    size_t base = ((size_t)b * HW + hw0 + p) * 64 + od * 8;
    *(uint4*)(xd + base) = a;
    *(uint4*)(xi + base) = bvec;
  }
}

// ---------------------------------------------------------------------------
// k_off: standalone om conv + bilinear params. 64-px tile, 512 thr, 1024 blk.
// B-fragments direct from global xd/xi (predicated; r5-verified indexing).
// LDS: sPart 16384 B only -> wave-cap residency (32 waves/CU).
// Output pPar[blk][tap9][px64]{w0,w1,of} packed u32 (7 MB workspace).
// ---------------------------------------------------------------------------
__global__ __launch_bounds__(512, 4) void k_off(const short* __restrict__ xd,
                                                const short* __restrict__ xi,
                                                const short* __restrict__ wtbomF,
                                                const float* __restrict__ b_om,
                                                unsigned* __restrict__ pPar) {
  __shared__ float sPart[4096];                  // [kh2][32r][64c]
  const int blk = (int)(blockIdx.x & 7) * 128 + (int)(blockIdx.x >> 3);
  const int b    = blk >> 8;
  const int tile = blk & 255;
  const int h0   = tile >> 1;
  const int x0   = (tile & 1) << 6;
  const int tid  = threadIdx.x;
  const int l15 = tid & 15, quad = (tid & 63) >> 4, wave = tid >> 6;
  const int kh = wave >> 2, wn = wave & 3;

  const short* xdb = xd + (size_t)b * HW * 64;
  const short* xib = xi + (size_t)b * HW * 64;

  // om GEMM M=32 N=64 K=1152, waves K(2) x N(4); B direct from global.
  {
    const int bx = x0 + wn * 16 + l15 - 1;
    floatx4 oa = {0.f,0.f,0.f,0.f}, oc = {0.f,0.f,0.f,0.f};
#pragma unroll
    for (int i = 0; i < 18; ++i) {
      int s = kh * 18 + i;                        // [0,36)
      int tap = s >> 2;
      int ty = tap / 3, tx = tap - ty * 3;
      int g = (s * 4 + quad) & 15;
      const short* aF = wtbomF + (size_t)s * 1024 + (quad * 16 + l15) * 8;
      half8 a0 = *(const half8*)aF;
      half8 a1 = *(const half8*)(aF + 512);
      int y = h0 + ty - 1;
      int x = bx + tx;
      uint4 bv = make_uint4(0, 0, 0, 0);
      if (((unsigned)y < 128u) && ((unsigned)x < 128u)) {
        const short* src = (g < 8 ? xdb : xib) + (size_t)(y * 128 + x) * 64 + (g & 7) * 8;
        bv = *(const uint4*)src;
      }
      half8 bb = *(half8*)&bv;
      oa = __builtin_amdgcn_mfma_f32_16x16x32_f16(a0, bb, oa, 0, 0, 0);
      oc = __builtin_amdgcn_mfma_f32_16x16x32_f16(a1, bb, oc, 0, 0, 0);
    }
    float* pw = sPart + kh * 2048 + wn * 16 + l15;
#pragma unroll
    for (int r = 0; r < 4; ++r) {
      int row0 = quad * 4 + r;
      pw[row0 * 64] = oa[r];
      int row1 = 16 + quad * 4 + r;
      if (row1 < 27) pw[row1 * 64] = oc[r];
    }
  }
  __syncthreads();

  // bilinear params -> global pPar
  unsigned* pB = pPar + (size_t)blk * 1728;
  for (int item = tid; item < 576; item += 512) {
    int k  = item >> 6;
    int px = item & 63;
    float dy = sPart[(2 * k) * 64 + px]     + sPart[2048 + (2 * k) * 64 + px]     + b_om[2 * k];
    float dx = sPart[(2 * k + 1) * 64 + px] + sPart[2048 + (2 * k + 1) * 64 + px] + b_om[2 * k + 1];
    float mr = sPart[(18 + k) * 64 + px]    + sPart[2048 + (18 + k) * 64 + px]    + b_om[18 + k];
    int h = h0, w = x0 + px;
    float m  = 1.f / (1.f + __expf(-mr));
    float py  = (float)(k / 3 - 1 + h) + dy;
    float pxx = (float)(k % 3 - 1 + w) + dx;
    float y0f = floorf(py), x0f = floorf(pxx);
    float fy = py - y0f, fx = pxx - x0f;
    int y0 = (int)y0f, x0c = (int)x0f;
    int y1 = y0 + 1, x1 = x0c + 1;
    float vy0 = ((unsigned)y0 < 128u) ? 1.f : 0.f;
    float vy1 = ((unsigned)y1 < 128u) ? 1.f : 0.f;
    float hx0 = ((unsigned)x0c < 128u) ? (1.f - fx) : 0.f;
    float hx1 = ((unsigned)x1 < 128u) ? fx : 0.f;
    int yc0 = min(max(y0, 0), 127), yc1 = min(max(y1, 0), 127);
    int xc0 = min(max(x0c, 0), 127), xc1 = min(max(x1, 0), 127);
    int xb  = min(xc0, 126);
    float wA = (xc0 == xb     ? hx0 : 0.f) + (xc1 == xb     ? hx1 : 0.f);
    float wB = (xc0 == xb + 1 ? hx0 : 0.f) + (xc1 == xb + 1 ? hx1 : 0.f);
    float gy0 = (1.f - fy) * vy0 * m, gy1 = fy * vy1 * m;
    int base = (k * 64 + px) * 3;
    pB[base + 0] = packh2(gy0 * wA, gy0 * wB);
    pB[base + 1] = packh2(gy1 * wA, gy1 * wB);
    pB[base + 2] = (unsigned)(yc0 * 128 + xb) | ((unsigned)(yc1 * 128 + xb) << 16);
  }
}

// ---------------------------------------------------------------------------
// k_main: gather + main GEMM only. 64-px tile, 512 thr, 1024 blk.
// LDS = 31488 B: sPar @0 (6912, live whole kernel), sV @6912 (24576, 3-tap
// chunks). Raw barriers (lgkmcnt-only) keep next-chunk gather loads in
// flight across E's MFMA phase (T14 issue-early/write-late).
// ---------------------------------------------------------------------------
__global__ __launch_bounds__(512, 6) void k_main(const short* __restrict__ xd,
                                                 const short* __restrict__ wtbF,
                                                 const unsigned* __restrict__ pPar,
                                                 const float* __restrict__ bias,
                                                 float* __restrict__ out) {
  __shared__ __align__(16) char smem[31488];
  unsigned* sPar = (unsigned*)smem;               // 1728 dwords
  short*    sV   = (short*)(smem + 6912);

  const int blk = (int)(blockIdx.x & 7) * 128 + (int)(blockIdx.x >> 3);
  const int b    = blk >> 8;
  const int tile = blk & 255;
  const int h0   = tile >> 1;
  const int x0   = (tile & 1) << 6;
  const int hw0  = h0 * 128 + x0;
  const int tid  = threadIdx.x;
  const int l15 = tid & 15, quad = (tid & 63) >> 4, wave = tid >> 6;

  const short* xdb = xd + (size_t)b * HW * 64;

  // ---- stage params into LDS (432 x uint4, coalesced) ----
  {
    const uint4* src = (const uint4*)(pPar + (size_t)blk * 1728);
    if (tid < 432) ((uint4*)sPar)[tid] = src[tid];
  }
  BAR_W();

  const int g0  = tid & 7;
  const int px1 = tid >> 3;                       // 0..63
  const short* xtb = xdb + g0 * 8;
  const int slot = (g0 ^ (px1 & 7)) * 8;
  const int wm = wave >> 1, wn2 = wave & 1;       // E: M(4) x N(2)
  const int afrag = (quad * 16 + l15) * 8;
  const int xkey = (l15 & 7);
  floatx4 acc00 = {0.f,0.f,0.f,0.f}, acc01 = {0.f,0.f,0.f,0.f};
  floatx4 acc10 = {0.f,0.f,0.f,0.f}, acc11 = {0.f,0.f,0.f,0.f};

#define LOADTAP(J, AA, BB, CC, DD)                                  \
  {                                                                 \
    unsigned of_ = sPar[((J) * 64 + px1) * 3 + 2];                  \
    const short* pa_ = xtb + (size_t)(of_ & 0xffff) * 64;           \
    const short* pb_ = xtb + (size_t)(of_ >> 16) * 64;              \
    AA = *(const uint4*)pa_;                                        \
    BB = *(const uint4*)(pa_ + 64);                                 \
    CC = *(const uint4*)pb_;                                        \
    DD = *(const uint4*)(pb_ + 64);                                 \
  }

#define MATHTAP(J, ROW, AA, BB, CC, DD)                             \
  {                                                                 \
    unsigned w0_ = sPar[((J) * 64 + px1) * 3 + 0];                  \
    unsigned w1_ = sPar[((J) * 64 + px1) * 3 + 1];                  \
    const unsigned* Au_ = (const unsigned*)&AA;                     \
    const unsigned* Bu_ = (const unsigned*)&BB;                     \
    const unsigned* Cu_ = (const unsigned*)&CC;                     \
    const unsigned* Du_ = (const unsigned*)&DD;                     \
    unsigned res_[4];                                               \
    _Pragma("unroll")                                               \
    for (int d_ = 0; d_ < 4; ++d_) {                                \
      unsigned acc_ = pk_mul_blo(Au_[d_], w0_);                     \
      acc_ = pk_fma_bhi(Bu_[d_], w0_, acc_);                        \
      acc_ = pk_fma_blo(Cu_[d_], w1_, acc_);                        \
      acc_ = pk_fma_bhi(Du_[d_], w1_, acc_);                        \
      res_[d_] = acc_;                                              \
    }                                                               \
    *(uint4*)(&sV[((ROW) * 64 + px1) * 64 + slot]) =                \
        make_uint4(res_[0], res_[1], res_[2], res_[3]);             \
  }

#define ESTEP(S, JL)                                                          \
  {                                                                           \
    const short* aF_ = wtbF + (size_t)((S) * 4 + wm) * 1024;                  \
    half8 a0_ = *(const half8*)(aF_ + afrag);                                 \
    half8 a1_ = *(const half8*)(aF_ + 512 + afrag);                           \
    int oct_ = (((S) & 1) * 4 + quad) ^ xkey;                                 \
    half8 bb0_ = *(const half8*)(&sV[((JL) * 64 + wn2 * 32 + l15) * 64 + oct_ * 8]);      \
    half8 bb1_ = *(const half8*)(&sV[((JL) * 64 + wn2 * 32 + 16 + l15) * 64 + oct_ * 8]); \
    acc00 = __builtin_amdgcn_mfma_f32_16x16x32_f16(a0_, bb0_, acc00, 0, 0, 0);\
    acc01 = __builtin_amdgcn_mfma_f32_16x16x32_f16(a0_, bb1_, acc01, 0, 0, 0);\
    acc10 = __builtin_amdgcn_mfma_f32_16x16x32_f16(a1_, bb0_, acc10, 0, 0, 0);\
    acc11 = __builtin_amdgcn_mfma_f32_16x16x32_f16(a1_, bb1_, acc11, 0, 0, 0);\
  }

  uint4 Aa, Ba, Ca, Da;                           // register set a
  uint4 Ab, Bb, Cb, Db;                           // register set b

  // ---- chunk 0: taps 0..2 ----
  LOADTAP(0, Aa, Ba, Ca, Da);
  LOADTAP(1, Ab, Bb, Cb, Db);
  MATHTAP(0, 0, Aa, Ba, Ca, Da);
  LOADTAP(2, Aa, Ba, Ca, Da);
  MATHTAP(1, 1, Ab, Bb, Cb, Db);
  LOADTAP(3, Ab, Bb, Cb, Db);                     // flies across E(0..5)
  MATHTAP(2, 2, Aa, Ba, Ca, Da);
  LOADTAP(4, Aa, Ba, Ca, Da);                     // flies across E(0..5)
  BAR_W();
  ESTEP(0, 0); ESTEP(1, 0); ESTEP(2, 1); ESTEP(3, 1); ESTEP(4, 2); ESTEP(5, 2);
  BAR_R();

  // ---- chunk 1: taps 3..5 ----
  MATHTAP(3, 0, Ab, Bb, Cb, Db);
  LOADTAP(5, Ab, Bb, Cb, Db);
  MATHTAP(4, 1, Aa, Ba, Ca, Da);
  LOADTAP(6, Aa, Ba, Ca, Da);                     // flies across E(6..11)
  MATHTAP(5, 2, Ab, Bb, Cb, Db);
  LOADTAP(7, Ab, Bb, Cb, Db);                     // flies across E(6..11)
  BAR_W();
  ESTEP(6, 0); ESTEP(7, 0); ESTEP(8, 1); ESTEP(9, 1); ESTEP(10, 2); ESTEP(11, 2);
  BAR_R();

  // ---- chunk 2: taps 6..8 ----
  MATHTAP(6, 0, Aa, Ba, Ca, Da);
  LOADTAP(8, Aa, Ba, Ca, Da);
  MATHTAP(7, 1, Ab, Bb, Cb, Db);
  MATHTAP(8, 2, Aa, Ba, Ca, Da);
  BAR_W();
  ESTEP(12, 0); ESTEP(13, 0); ESTEP(14, 1); ESTEP(15, 1); ESTEP(16, 2); ESTEP(17, 2);

#undef LOADTAP
#undef MATHTAP
#undef ESTEP

  // ---- epilogue ----
  float* outb = out + (size_t)b * COUT * HW + hw0 + wn2 * 32;
#pragma unroll
  for (int r = 0; r < 4; ++r) {
    int o = wm * 32 + quad * 4 + r;
    float bo = bias[o];
    outb[(size_t)o * HW + l15]      = acc00[r] + bo;
    outb[(size_t)o * HW + 16 + l15] = acc01[r] + bo;
    int o1 = o + 16;
    float bo1 = bias[o1];
    outb[(size_t)o1 * HW + l15]      = acc10[r] + bo1;
    outb[(size_t)o1 * HW + 16 + l15] = acc11[r] + bo1;
  }
}

// ---------------------------------------------------------------------------
extern "C" void kernel_launch(void* const* d_in, const int* in_sizes, int n_in,
                              void* d_out, int out_size, void* d_ws, size_t ws_size,
                              hipStream_t stream) {
  const float* input_feat = (const float*)d_in[0];  // [4,64,128,128]
  const float* inter      = (const float*)d_in[1];  // [4,64,128,128]
  const float* weight     = (const float*)d_in[2];  // [128,64,3,3]
  const float* bias       = (const float*)d_in[3];  // [128]
  const float* w_om       = (const float*)d_in[4];  // [27,128,3,3]
  const float* b_om       = (const float*)d_in[5];  // [27]
  float* out = (float*)d_out;                       // [4,128,128,128]

  short*    wtbF   = (short*)d_ws;                          // 147456 B
  short*    wtbomF = (short*)((char*)d_ws + 147456);        // 73728 B
  short*    xd     = (short*)((char*)d_ws + 221184);        // 8388608 B
  short*    xi     = (short*)((char*)d_ws + 8609792);       // 8388608 B
  unsigned* pPar   = (unsigned*)((char*)d_ws + 16998400);   // 7077888 B (~24 MB)

  k_tr<<<NB * (HW / 64), 256, 0, stream>>>(input_feat, inter, weight, w_om,
                                           xd, xi, wtbF, wtbomF);
  k_off<<<NB * (HW / 64), 512, 0, stream>>>(xd, xi, wtbomF, b_om, pPar);
  k_main<<<NB * (HW / 64), 512, 0, stream>>>(xd, wtbF, pPar, bias, out);
}

// Round 8
// 128.558 us; speedup vs baseline: 1.6791x; 1.6791x over previous
//
#include <hip/hip_runtime.h>
#include <hip/hip_fp16.h>

// B=4, Cin=64, Cout=128, H=W=128, 3x3, stride=1, pad=1, dil=1
#define HW    16384
#define NB    4
#define CIN   64
#define COUT  128

typedef short  short8  __attribute__((ext_vector_type(8)));
typedef _Float16 half8 __attribute__((ext_vector_type(8)));
typedef float  floatx4 __attribute__((ext_vector_type(4)));

__device__ __forceinline__ unsigned packh2(float a, float b) {
  __half2 h = __floats2half2_rn(a, b);
  return *(unsigned*)&h;
}
__device__ __forceinline__ short f2h(float f) {
  __half h = __float2half(f);
  return *(short*)&h;
}

// ---- packed-f16 bilinear helpers: broadcast one half of w via op_sel ----
__device__ __forceinline__ unsigned pk_mul_blo(unsigned a, unsigned w) {
  unsigned d;
  asm("v_pk_mul_f16 %0, %1, %2 op_sel:[0,0] op_sel_hi:[1,0]"
      : "=v"(d) : "v"(a), "v"(w));
  return d;
}
__device__ __forceinline__ unsigned pk_fma_blo(unsigned a, unsigned w, unsigned c) {
  unsigned d;
  asm("v_pk_fma_f16 %0, %1, %2, %3 op_sel:[0,0,0] op_sel_hi:[1,0,1]"
      : "=v"(d) : "v"(a), "v"(w), "v"(c));
  return d;
}
__device__ __forceinline__ unsigned pk_fma_bhi(unsigned a, unsigned w, unsigned c) {
  unsigned d;
  asm("v_pk_fma_f16 %0, %1, %2, %3 op_sel:[0,1,0] op_sel_hi:[1,1,1]"
      : "=v"(d) : "v"(a), "v"(w), "v"(c));
  return d;
}

// ---------------------------------------------------------------------------
// k_tr: CHW fp32 -> HWC f16 (xd=input_feat, xi=inter) + fused weight prep.
// float2-vectorized global loads (8 B/lane, G13), 16 load insts/thread.
//  wtbF   [s18][wave4][tile2][quad4][l16][8] ; k=s*32+q*8+i, c=k&63,  tap=k>>6
//  wtbomF [s36][tile2][quad4][l16][8]        ; k=s*32+q*8+i, c=k&127, tap=k>>7
// ---------------------------------------------------------------------------
__global__ __launch_bounds__(256) void k_tr(const float* __restrict__ x,
                                            const float* __restrict__ inter,
                                            const float* __restrict__ weight,
                                            const float* __restrict__ w_om,
                                            short* __restrict__ xd,
                                            short* __restrict__ xi,
                                            short* __restrict__ wtbF,
                                            short* __restrict__ wtbomF) {
  __shared__ unsigned sT[64][65];                 // 64 px x 64 cp (+pad)
  const int blk = blockIdx.x;
  const int b = blk >> 8, hw0 = (blk & 255) * 64;
  const int tid = threadIdx.x;
  const int pp = tid & 31;                        // px pair 0..31
  const int cg = tid >> 5;                        // 0..7
  const float* s0 = x     + (size_t)b * CIN * HW + hw0 + pp * 2;
  const float* s1 = inter + (size_t)b * CIN * HW + hw0 + pp * 2;
#pragma unroll
  for (int t = 0; t < 8; ++t) {
    int cp = t * 8 + cg;                          // 0..63
    const float* s = (cp < 32) ? (s0 + (cp * 2) * HW)
                               : (s1 + ((cp - 32) * 2) * HW);
    float2 a = *(const float2*)s;                 // ch c,   px pp*2..+1
    float2 c2 = *(const float2*)(s + HW);         // ch c+1, px pp*2..+1
    sT[pp * 2 + 0][cp] = packh2(a.x, c2.x);
    sT[pp * 2 + 1][cp] = packh2(a.y, c2.y);
  }
  // fused weight prep while LDS settles
  {
    int i = blk * 256 + tid;
    if (i < 73728) {
      int i8 = i & 7, l = (i >> 3) & 15, q = (i >> 7) & 3;
      int t = (i >> 9) & 1, wv = (i >> 10) & 3, s = i >> 12;
      int o = wv * 32 + t * 16 + l;
      int k = s * 32 + q * 8 + i8;
      int c = k & 63, tap = k >> 6;
      wtbF[i] = f2h(weight[o * 576 + c * 9 + tap]);
    }
    if (i < 36864) {
      int i8 = i & 7, l = (i >> 3) & 15, q = (i >> 7) & 3;
      int t = (i >> 9) & 1, s = i >> 10;
      int o = t * 16 + l;
      int k = s * 32 + q * 8 + i8;
      int c = k & 127, tap = k >> 7;
      wtbomF[i] = (o < 27) ? f2h(w_om[o * 1152 + c * 9 + tap]) : (short)0;
    }
  }
  __syncthreads();
  const int od = tid & 7, p0 = tid >> 3;
#pragma unroll
  for (int it = 0; it < 2; ++it) {
    int p = p0 + it * 32;
    uint4 a, bvec;
    a.x = sT[p][od * 4 + 0]; a.y = sT[p][od * 4 + 1];
    a.z = sT[p][od * 4 + 2]; a.w = sT[p][od * 4 + 3];
    bvec.x = sT[p][32 + od * 4 + 0]; bvec.y = sT[p][32 + od * 4 + 1];
    bvec.z = sT[p][32 + od * 4 + 2]; bvec.w = sT[p][32 + od * 4 + 3];
    size_t base = ((size_t)b * HW + hw0 + p) * 64 + od * 8;
    *(uint4*)(xd + base) = a;
    *(uint4*)(xi + base) = bvec;
  }
}

// ---------------------------------------------------------------------------
// k_dcn: FUSED offset/mask conv + modulated deformable conv. 64-px tile,
// 512 threads (8 waves), 1024 blocks, XCD-swizzled blockIdx.
// (Round-4 structure — best measured — plus s_setprio around MFMA clusters.)
// LDS = 50688 B -> 3 blocks/CU (24 waves/CU):
//  sH    @0      halo 3x66x128ch f16             50688 B (live A->B)
//  sPart @0      om partials [kh2][32r][64c] f32 16384 B (live postB->C)
//  sPar  @40960  packed bilinear params           6912 B (live C->D2, above sV)
//  sV    @0      V panel [tapLoc*64+px][64] XOR  <=40960 B (5-tap / 4-tap halves)
// Phase B: om GEMM M=32 N=64 K=1152, waves = K(2) x N(4), 36 MFMA each.
// Phase E: main GEMM M=128 N=64 K=576, waves = M(4) x N(2), 18 steps.
// Phase D1/E1: gather taps 0-4, GEMM s=0..9;  D2/E2: taps 5-8, s=10..17.
// ---------------------------------------------------------------------------
__global__ __launch_bounds__(512, 6) void k_dcn(const short* __restrict__ xd,
                                                const short* __restrict__ xi,
                                                const short* __restrict__ wtbF,
                                                const short* __restrict__ wtbomF,
                                                const float* __restrict__ b_om,
                                                const float* __restrict__ bias,
                                                float* __restrict__ out) {
  __shared__ __align__(16) char smem[50688];
  short*    sH    = (short*)smem;
  float*    sPart = (float*)smem;                 // over dead sH, after bar2
  unsigned* sPar  = (unsigned*)(smem + 40960);    // above sV window
  short*    sV    = (short*)smem;

  // XCD-aware swizzle: 1024 blocks -> 128-block contiguous chunk per XCD
  const int blk = (int)(blockIdx.x & 7) * 128 + (int)(blockIdx.x >> 3);
  const int b    = blk >> 8;
  const int tile = blk & 255;                     // 2 tiles per image row
  const int h0   = tile >> 1;
  const int x0   = (tile & 1) << 6;
  const int hw0  = h0 * 128 + x0;
  const int tid  = threadIdx.x;
  const int l15 = tid & 15, quad = (tid & 63) >> 4, wave = tid >> 6;

  const short* xdb = xd + (size_t)b * HW * 64;
  const short* xib = xi + (size_t)b * HW * 64;

  // ---- phase A: halo patch 3 rows x 66 cols x 128 ch ----
  for (int item = tid; item < 3168; item += 512) {
    int g = item & 15, prow = item >> 4;        // prow = r3*66 + c66
    int r3 = prow / 66, c66 = prow - r3 * 66;
    int y = h0 + r3 - 1;
    int x = x0 + c66 - 1;
    uint4 v = make_uint4(0, 0, 0, 0);
    if (((unsigned)y < 128u) && ((unsigned)x < 128u)) {
      const short* src = (g < 8)
          ? (xdb + (size_t)(y * 128 + x) * 64 + g * 8)
          : (xib + (size_t)(y * 128 + x) * 64 + (g - 8) * 8);
      v = *(const uint4*)src;
    }
    *(uint4*)(&sH[(g * 198 + prow) * 8]) = v;
  }
  __syncthreads();                               // bar1: sH ready

  // ---- phase B: om GEMM, wave = (kh = wave>>2) x (wn = wave&3) ----
  {
    const int kh = wave >> 2, wn = wave & 3;
    floatx4 oa = {0.f,0.f,0.f,0.f}, oc = {0.f,0.f,0.f,0.f};
    __builtin_amdgcn_s_setprio(1);
#pragma unroll
    for (int i = 0; i < 18; ++i) {
      int s = kh * 18 + i;                      // [0,36)
      int tap = s >> 2;
      int ty = tap / 3, tx = tap % 3;
      int g = (s * 4 + quad) & 15;
      const short* aF = wtbomF + (size_t)s * 1024 + (quad * 16 + l15) * 8;
      half8 a0 = *(const half8*)aF;
      half8 a1 = *(const half8*)(aF + 512);
      half8 bb = *(const half8*)(&sH[(g * 198 + ty * 66 + tx + wn * 16 + l15) * 8]);
      oa = __builtin_amdgcn_mfma_f32_16x16x32_f16(a0, bb, oa, 0, 0, 0);
      oc = __builtin_amdgcn_mfma_f32_16x16x32_f16(a1, bb, oc, 0, 0, 0);
    }
    __builtin_amdgcn_s_setprio(0);
    __syncthreads();                             // bar2: sH dead, Part free
    float* pw = sPart + kh * 2048 + wn * 16 + l15;
#pragma unroll
    for (int r = 0; r < 4; ++r) {
      int row0 = quad * 4 + r;                  // tile 0 rows: 0..15
      pw[row0 * 64] = oa[r];
      int row1 = 16 + quad * 4 + r;             // tile 1 rows: 16..31
      if (row1 < 27) pw[row1 * 64] = oc[r];
    }
  }
  __syncthreads();                               // bar3: Part ready

  // ---- phase C: bilinear params (reduce K-halves + b_om inline) ----
  for (int item = tid; item < 576; item += 512) {
    int k  = item >> 6;
    int px = item & 63;
    float dy = sPart[(2 * k) * 64 + px]     + sPart[2048 + (2 * k) * 64 + px]     + b_om[2 * k];
    float dx = sPart[(2 * k + 1) * 64 + px] + sPart[2048 + (2 * k + 1) * 64 + px] + b_om[2 * k + 1];
    float mr = sPart[(18 + k) * 64 + px]    + sPart[2048 + (18 + k) * 64 + px]    + b_om[18 + k];
    int h = h0, w = x0 + px;
    float m  = 1.f / (1.f + __expf(-mr));
    float py  = (float)(k / 3 - 1 + h) + dy;
    float pxx = (float)(k % 3 - 1 + w) + dx;
    float y0f = floorf(py), x0f = floorf(pxx);
    float fy = py - y0f, fx = pxx - x0f;
    int y0 = (int)y0f, x0c = (int)x0f;
    int y1 = y0 + 1, x1 = x0c + 1;
    float vy0 = ((unsigned)y0 < 128u) ? 1.f : 0.f;
    float vy1 = ((unsigned)y1 < 128u) ? 1.f : 0.f;
    float hx0 = ((unsigned)x0c < 128u) ? (1.f - fx) : 0.f;
    float hx1 = ((unsigned)x1 < 128u) ? fx : 0.f;
    int yc0 = min(max(y0, 0), 127), yc1 = min(max(y1, 0), 127);
    int xc0 = min(max(x0c, 0), 127), xc1 = min(max(x1, 0), 127);
    int xb  = min(xc0, 126);
    float wA = (xc0 == xb     ? hx0 : 0.f) + (xc1 == xb     ? hx1 : 0.f);
    float wB = (xc0 == xb + 1 ? hx0 : 0.f) + (xc1 == xb + 1 ? hx1 : 0.f);
    float gy0 = (1.f - fy) * vy0 * m, gy1 = fy * vy1 * m;
    int base = (k * 64 + px) * 3;
    sPar[base + 0] = packh2(gy0 * wA, gy0 * wB);
    sPar[base + 1] = packh2(gy1 * wA, gy1 * wB);
    sPar[base + 2] = (unsigned)(yc0 * 128 + xb) | ((unsigned)(yc1 * 128 + xb) << 16);
  }
  __syncthreads();                               // bar4: Par ready, Part dead

  const int g0  = tid & 7;
  const int px1 = tid >> 3;                      // 0..63
  const short* xtb = xdb + g0 * 8;
  const int slot = (g0 ^ (px1 & 7)) * 8;
  const int wm = wave >> 1, wn2 = wave & 1;      // E: M(4) x N(2)
  const int afrag = (quad * 16 + l15) * 8;
  const int xkey = (l15 & 7);
  floatx4 acc00 = {0.f,0.f,0.f,0.f}, acc01 = {0.f,0.f,0.f,0.f};
  floatx4 acc10 = {0.f,0.f,0.f,0.f}, acc11 = {0.f,0.f,0.f,0.f};

#pragma unroll
  for (int half = 0; half < 2; ++half) {
    const int j0 = half ? 5 : 0;
    const int jn = half ? 4 : 5;
    const int s0 = half ? 10 : 0;
    const int sn = half ? 8 : 10;

    // ---- phase D: gather jn taps x 8ch/thread, packed-f16 bilinear ----
#pragma unroll 3
    for (int jl = 0; jl < jn; ++jl) {
      int j = j0 + jl;
      int pbase = (j * 64 + px1) * 3;
      unsigned w0 = sPar[pbase + 0];             // (gy0*wA, gy0*wB) f16x2
      unsigned w1 = sPar[pbase + 1];             // (gy1*wA, gy1*wB) f16x2
      unsigned of = sPar[pbase + 2];
      int offA = of & 0xffff, offB = of >> 16;
      const short* pa = xtb + (size_t)offA * 64;
      const short* pb = xtb + (size_t)offB * 64;
      uint4 A  = *(const uint4*)pa;
      uint4 Bv = *(const uint4*)(pa + 64);
      uint4 C  = *(const uint4*)pb;
      uint4 D  = *(const uint4*)(pb + 64);
      unsigned res[4];
      const unsigned* Au = (const unsigned*)&A;
      const unsigned* Bu = (const unsigned*)&Bv;
      const unsigned* Cu = (const unsigned*)&C;
      const unsigned* Du = (const unsigned*)&D;
#pragma unroll
      for (int d = 0; d < 4; ++d) {
        unsigned acc = pk_mul_blo(Au[d], w0);
        acc = pk_fma_bhi(Bu[d], w0, acc);
        acc = pk_fma_blo(Cu[d], w1, acc);
        acc = pk_fma_bhi(Du[d], w1, acc);
        res[d] = acc;
      }
      *(uint4*)(&sV[(jl * 64 + px1) * 64 + slot]) =
          make_uint4(res[0], res[1], res[2], res[3]);
    }
    __syncthreads();                             // sV half ready

    // ---- phase E: main GEMM half ----
    __builtin_amdgcn_s_setprio(1);
#pragma unroll 5
    for (int si = 0; si < sn; ++si) {
      int s = s0 + si;
      const short* aF = wtbF + (size_t)(s * 4 + wm) * 1024;
      half8 a0 = *(const half8*)(aF + afrag);
      half8 a1 = *(const half8*)(aF + 512 + afrag);
      int jl = (s >> 1) - j0;
      int oct = ((s & 1) * 4 + quad) ^ xkey;    // swizzled octet slot
      half8 bb0 = *(const half8*)(&sV[(jl * 64 + wn2 * 32 + l15) * 64 + oct * 8]);
      half8 bb1 = *(const half8*)(&sV[(jl * 64 + wn2 * 32 + 16 + l15) * 64 + oct * 8]);
      acc00 = __builtin_amdgcn_mfma_f32_16x16x32_f16(a0, bb0, acc00, 0, 0, 0);
      acc01 = __builtin_amdgcn_mfma_f32_16x16x32_f16(a0, bb1, acc01, 0, 0, 0);
      acc10 = __builtin_amdgcn_mfma_f32_16x16x32_f16(a1, bb0, acc10, 0, 0, 0);
      acc11 = __builtin_amdgcn_mfma_f32_16x16x32_f16(a1, bb1, acc11, 0, 0, 0);
    }
    __builtin_amdgcn_s_setprio(0);
    if (half == 0) __syncthreads();              // E1 done reading before D2 writes
  }

  // ---- epilogue ----
  float* outb = out + (size_t)b * COUT * HW + hw0 + wn2 * 32;
#pragma unroll
  for (int r = 0; r < 4; ++r) {
    int o = wm * 32 + quad * 4 + r;
    float bo = bias[o];
    outb[(size_t)o * HW + l15]      = acc00[r] + bo;
    outb[(size_t)o * HW + 16 + l15] = acc01[r] + bo;
    int o1 = o + 16;
    float bo1 = bias[o1];
    outb[(size_t)o1 * HW + l15]      = acc10[r] + bo1;
    outb[(size_t)o1 * HW + 16 + l15] = acc11[r] + bo1;
  }
}

// ---------------------------------------------------------------------------
extern "C" void kernel_launch(void* const* d_in, const int* in_sizes, int n_in,
                              void* d_out, int out_size, void* d_ws, size_t ws_size,
                              hipStream_t stream) {
  const float* input_feat = (const float*)d_in[0];  // [4,64,128,128]
  const float* inter      = (const float*)d_in[1];  // [4,64,128,128]
  const float* weight     = (const float*)d_in[2];  // [128,64,3,3]
  const float* bias       = (const float*)d_in[3];  // [128]
  const float* w_om       = (const float*)d_in[4];  // [27,128,3,3]
  const float* b_om       = (const float*)d_in[5];  // [27]
  float* out = (float*)d_out;                       // [4,128,128,128]

  short* wtbF   = (short*)d_ws;                          // 147456 B
  short* wtbomF = (short*)((char*)d_ws + 147456);        // 73728 B
  short* xd     = (short*)((char*)d_ws + 221184);        // 8388608 B
  short* xi     = (short*)((char*)d_ws + 8609792);       // 8388608 B (~17 MB)

  k_tr<<<NB * (HW / 64), 256, 0, stream>>>(input_feat, inter, weight, w_om,
                                           xd, xi, wtbF, wtbomF);
  k_dcn<<<NB * (HW / 64), 512, 0, stream>>>(xd, xi, wtbF, wtbomF, b_om, bias, out);
}

// Round 10
// 124.931 us; speedup vs baseline: 1.7279x; 1.0290x over previous
//
#include <hip/hip_runtime.h>
#include <hip/hip_fp16.h>

// B=4, Cin=64, Cout=128, H=W=128, 3x3, stride=1, pad=1, dil=1
#define HW    16384
#define NB    4
#define CIN   64
#define COUT  128

typedef short  short8  __attribute__((ext_vector_type(8)));
typedef _Float16 half8 __attribute__((ext_vector_type(8)));
typedef float  floatx4 __attribute__((ext_vector_type(4)));

__device__ __forceinline__ unsigned packh2(float a, float b) {
  __half2 h = __floats2half2_rn(a, b);
  return *(unsigned*)&h;
}
__device__ __forceinline__ short f2h(float f) {
  __half h = __float2half(f);
  return *(short*)&h;
}

// ---- packed-f16 bilinear helpers: broadcast one half of w via op_sel ----
__device__ __forceinline__ unsigned pk_mul_blo(unsigned a, unsigned w) {
  unsigned d;
  asm("v_pk_mul_f16 %0, %1, %2 op_sel:[0,0] op_sel_hi:[1,0]"
      : "=v"(d) : "v"(a), "v"(w));
  return d;
}
__device__ __forceinline__ unsigned pk_fma_blo(unsigned a, unsigned w, unsigned c) {
  unsigned d;
  asm("v_pk_fma_f16 %0, %1, %2, %3 op_sel:[0,0,0] op_sel_hi:[1,0,1]"
      : "=v"(d) : "v"(a), "v"(w), "v"(c));
  return d;
}
__device__ __forceinline__ unsigned pk_fma_bhi(unsigned a, unsigned w, unsigned c) {
  unsigned d;
  asm("v_pk_fma_f16 %0, %1, %2, %3 op_sel:[0,1,0] op_sel_hi:[1,1,1]"
      : "=v"(d) : "v"(a), "v"(w), "v"(c));
  return d;
}

// ---------------------------------------------------------------------------
// k_tr: CHW fp32 -> HWC f16 (xd=input_feat, xi=inter) + fused weight prep.
// float2-vectorized global loads (8 B/lane, G13), 16 load insts/thread.
//  wtbF   [s18][wave4][tile2][quad4][l16][8] ; k=s*32+q*8+i, c=k&63,  tap=k>>6
//  wtbomF [s36][tile2][quad4][l16][8]        ; k=s*32+q*8+i, c=k&127, tap=k>>7
// ---------------------------------------------------------------------------
__global__ __launch_bounds__(256) void k_tr(const float* __restrict__ x,
                                            const float* __restrict__ inter,
                                            const float* __restrict__ weight,
                                            const float* __restrict__ w_om,
                                            short* __restrict__ xd,
                                            short* __restrict__ xi,
                                            short* __restrict__ wtbF,
                                            short* __restrict__ wtbomF) {
  __shared__ unsigned sT[64][65];                 // 64 px x 64 cp (+pad)
  const int blk = blockIdx.x;
  const int b = blk >> 8, hw0 = (blk & 255) * 64;
  const int tid = threadIdx.x;
  const int pp = tid & 31;                        // px pair 0..31
  const int cg = tid >> 5;                        // 0..7
  const float* s0 = x     + (size_t)b * CIN * HW + hw0 + pp * 2;
  const float* s1 = inter + (size_t)b * CIN * HW + hw0 + pp * 2;
#pragma unroll
  for (int t = 0; t < 8; ++t) {
    int cp = t * 8 + cg;                          // 0..63
    const float* s = (cp < 32) ? (s0 + (cp * 2) * HW)
                               : (s1 + ((cp - 32) * 2) * HW);
    float2 a = *(const float2*)s;                 // ch c,   px pp*2..+1
    float2 c2 = *(const float2*)(s + HW);         // ch c+1, px pp*2..+1
    sT[pp * 2 + 0][cp] = packh2(a.x, c2.x);
    sT[pp * 2 + 1][cp] = packh2(a.y, c2.y);
  }
  // fused weight prep while LDS settles
  {
    int i = blk * 256 + tid;
    if (i < 73728) {
      int i8 = i & 7, l = (i >> 3) & 15, q = (i >> 7) & 3;
      int t = (i >> 9) & 1, wv = (i >> 10) & 3, s = i >> 12;
      int o = wv * 32 + t * 16 + l;
      int k = s * 32 + q * 8 + i8;
      int c = k & 63, tap = k >> 6;
      wtbF[i] = f2h(weight[o * 576 + c * 9 + tap]);
    }
    if (i < 36864) {
      int i8 = i & 7, l = (i >> 3) & 15, q = (i >> 7) & 3;
      int t = (i >> 9) & 1, s = i >> 10;
      int o = t * 16 + l;
      int k = s * 32 + q * 8 + i8;
      int c = k & 127, tap = k >> 7;
      wtbomF[i] = (o < 27) ? f2h(w_om[o * 1152 + c * 9 + tap]) : (short)0;
    }
  }
  __syncthreads();
  const int od = tid & 7, p0 = tid >> 3;
#pragma unroll
  for (int it = 0; it < 2; ++it) {
    int p = p0 + it * 32;
    uint4 a, bvec;
    a.x = sT[p][od * 4 + 0]; a.y = sT[p][od * 4 + 1];
    a.z = sT[p][od * 4 + 2]; a.w = sT[p][od * 4 + 3];
    bvec.x = sT[p][32 + od * 4 + 0]; bvec.y = sT[p][32 + od * 4 + 1];
    bvec.z = sT[p][32 + od * 4 + 2]; bvec.w = sT[p][32 + od * 4 + 3];
    size_t base = ((size_t)b * HW + hw0 + p) * 64 + od * 8;
    *(uint4*)(xd + base) = a;
    *(uint4*)(xi + base) = bvec;
  }
}

// ---------------------------------------------------------------------------
// k_dcn: FUSED offset/mask conv + modulated deformable conv. 64-px tile,
// 512 threads (8 waves), 1024 blocks, XCD-swizzled blockIdx.
// (Exact round-4 structure — measured best. No setprio: A/B r4 vs r8 showed
//  setprio around B/E MFMA clusters costs ~5 us at this 3-block/CU regime.)
// LDS = 50688 B -> 3 blocks/CU (24 waves/CU):
//  sH    @0      halo 3x66x128ch f16             50688 B (live A->B)
//  sPart @0      om partials [kh2][32r][64c] f32 16384 B (live postB->C)
//  sPar  @40960  packed bilinear params           6912 B (live C->D2, above sV)
//  sV    @0      V panel [tapLoc*64+px][64] XOR  <=40960 B (5-tap / 4-tap halves)
// Phase B: om GEMM M=32 N=64 K=1152, waves = K(2) x N(4), 36 MFMA each.
// Phase E: main GEMM M=128 N=64 K=576, waves = M(4) x N(2), 18 steps.
// Phase D1/E1: gather taps 0-4, GEMM s=0..9;  D2/E2: taps 5-8, s=10..17.
// ---------------------------------------------------------------------------
__global__ __launch_bounds__(512, 6) void k_dcn(const short* __restrict__ xd,
                                                const short* __restrict__ xi,
                                                const short* __restrict__ wtbF,
                                                const short* __restrict__ wtbomF,
                                                const float* __restrict__ b_om,
                                                const float* __restrict__ bias,
                                                float* __restrict__ out) {
  __shared__ __align__(16) char smem[50688];
  short*    sH    = (short*)smem;
  float*    sPart = (float*)smem;                 // over dead sH, after bar2
  unsigned* sPar  = (unsigned*)(smem + 40960);    // above sV window
  short*    sV    = (short*)smem;

  // XCD-aware swizzle: 1024 blocks -> 128-block contiguous chunk per XCD
  const int blk = (int)(blockIdx.x & 7) * 128 + (int)(blockIdx.x >> 3);
  const int b    = blk >> 8;
  const int tile = blk & 255;                     // 2 tiles per image row
  const int h0   = tile >> 1;
  const int x0   = (tile & 1) << 6;
  const int hw0  = h0 * 128 + x0;
  const int tid  = threadIdx.x;
  const int l15 = tid & 15, quad = (tid & 63) >> 4, wave = tid >> 6;

  const short* xdb = xd + (size_t)b * HW * 64;
  const short* xib = xi + (size_t)b * HW * 64;

  // ---- phase A: halo patch 3 rows x 66 cols x 128 ch ----
  for (int item = tid; item < 3168; item += 512) {
    int g = item & 15, prow = item >> 4;        // prow = r3*66 + c66
    int r3 = prow / 66, c66 = prow - r3 * 66;
    int y = h0 + r3 - 1;
    int x = x0 + c66 - 1;
    uint4 v = make_uint4(0, 0, 0, 0);
    if (((unsigned)y < 128u) && ((unsigned)x < 128u)) {
      const short* src = (g < 8)
          ? (xdb + (size_t)(y * 128 + x) * 64 + g * 8)
          : (xib + (size_t)(y * 128 + x) * 64 + (g - 8) * 8);
      v = *(const uint4*)src;
    }
    *(uint4*)(&sH[(g * 198 + prow) * 8]) = v;
  }
  __syncthreads();                               // bar1: sH ready

  // ---- phase B: om GEMM, wave = (kh = wave>>2) x (wn = wave&3) ----
  {
    const int kh = wave >> 2, wn = wave & 3;
    floatx4 oa = {0.f,0.f,0.f,0.f}, oc = {0.f,0.f,0.f,0.f};
#pragma unroll
    for (int i = 0; i < 18; ++i) {
      int s = kh * 18 + i;                      // [0,36)
      int tap = s >> 2;
      int ty = tap / 3, tx = tap % 3;
      int g = (s * 4 + quad) & 15;
      const short* aF = wtbomF + (size_t)s * 1024 + (quad * 16 + l15) * 8;
      half8 a0 = *(const half8*)aF;
      half8 a1 = *(const half8*)(aF + 512);
      half8 bb = *(const half8*)(&sH[(g * 198 + ty * 66 + tx + wn * 16 + l15) * 8]);
      oa = __builtin_amdgcn_mfma_f32_16x16x32_f16(a0, bb, oa, 0, 0, 0);
      oc = __builtin_amdgcn_mfma_f32_16x16x32_f16(a1, bb, oc, 0, 0, 0);
    }
    __syncthreads();                             // bar2: sH dead, Part free
    float* pw = sPart + kh * 2048 + wn * 16 + l15;
#pragma unroll
    for (int r = 0; r < 4; ++r) {
      int row0 = quad * 4 + r;                  // tile 0 rows: 0..15
      pw[row0 * 64] = oa[r];
      int row1 = 16 + quad * 4 + r;             // tile 1 rows: 16..31
      if (row1 < 27) pw[row1 * 64] = oc[r];
    }
  }
  __syncthreads();                               // bar3: Part ready

  // ---- phase C: bilinear params (reduce K-halves + b_om inline) ----
  for (int item = tid; item < 576; item += 512) {
    int k  = item >> 6;
    int px = item & 63;
    float dy = sPart[(2 * k) * 64 + px]     + sPart[2048 + (2 * k) * 64 + px]     + b_om[2 * k];
    float dx = sPart[(2 * k + 1) * 64 + px] + sPart[2048 + (2 * k + 1) * 64 + px] + b_om[2 * k + 1];
    float mr = sPart[(18 + k) * 64 + px]    + sPart[2048 + (18 + k) * 64 + px]    + b_om[18 + k];
    int h = h0, w = x0 + px;
    float m  = 1.f / (1.f + __expf(-mr));
    float py  = (float)(k / 3 - 1 + h) + dy;
    float pxx = (float)(k % 3 - 1 + w) + dx;
    float y0f = floorf(py), x0f = floorf(pxx);
    float fy = py - y0f, fx = pxx - x0f;
    int y0 = (int)y0f, x0c = (int)x0f;
    int y1 = y0 + 1, x1 = x0c + 1;
    float vy0 = ((unsigned)y0 < 128u) ? 1.f : 0.f;
    float vy1 = ((unsigned)y1 < 128u) ? 1.f : 0.f;
    float hx0 = ((unsigned)x0c < 128u) ? (1.f - fx) : 0.f;
    float hx1 = ((unsigned)x1 < 128u) ? fx : 0.f;
    int yc0 = min(max(y0, 0), 127), yc1 = min(max(y1, 0), 127);
    int xc0 = min(max(x0c, 0), 127), xc1 = min(max(x1, 0), 127);
    int xb  = min(xc0, 126);
    float wA = (xc0 == xb     ? hx0 : 0.f) + (xc1 == xb     ? hx1 : 0.f);
    float wB = (xc0 == xb + 1 ? hx0 : 0.f) + (xc1 == xb + 1 ? hx1 : 0.f);
    float gy0 = (1.f - fy) * vy0 * m, gy1 = fy * vy1 * m;
    int base = (k * 64 + px) * 3;
    sPar[base + 0] = packh2(gy0 * wA, gy0 * wB);
    sPar[base + 1] = packh2(gy1 * wA, gy1 * wB);
    sPar[base + 2] = (unsigned)(yc0 * 128 + xb) | ((unsigned)(yc1 * 128 + xb) << 16);
  }
  __syncthreads();                               // bar4: Par ready, Part dead

  const int g0  = tid & 7;
  const int px1 = tid >> 3;                      // 0..63
  const short* xtb = xdb + g0 * 8;
  const int slot = (g0 ^ (px1 & 7)) * 8;
  const int wm = wave >> 1, wn2 = wave & 1;      // E: M(4) x N(2)
  const int afrag = (quad * 16 + l15) * 8;
  const int xkey = (l15 & 7);
  floatx4 acc00 = {0.f,0.f,0.f,0.f}, acc01 = {0.f,0.f,0.f,0.f};
  floatx4 acc10 = {0.f,0.f,0.f,0.f}, acc11 = {0.f,0.f,0.f,0.f};

#pragma unroll
  for (int half = 0; half < 2; ++half) {
    const int j0 = half ? 5 : 0;
    const int jn = half ? 4 : 5;
    const int s0 = half ? 10 : 0;
    const int sn = half ? 8 : 10;

    // ---- phase D: gather jn taps x 8ch/thread, packed-f16 bilinear ----
#pragma unroll 3
    for (int jl = 0; jl < jn; ++jl) {
      int j = j0 + jl;
      int pbase = (j * 64 + px1) * 3;
      unsigned w0 = sPar[pbase + 0];             // (gy0*wA, gy0*wB) f16x2
      unsigned w1 = sPar[pbase + 1];             // (gy1*wA, gy1*wB) f16x2
      unsigned of = sPar[pbase + 2];
      int offA = of & 0xffff, offB = of >> 16;
      const short* pa = xtb + (size_t)offA * 64;
      const short* pb = xtb + (size_t)offB * 64;
      uint4 A  = *(const uint4*)pa;
      uint4 Bv = *(const uint4*)(pa + 64);
      uint4 C  = *(const uint4*)pb;
      uint4 D  = *(const uint4*)(pb + 64);
      unsigned res[4];
      const unsigned* Au = (const unsigned*)&A;
      const unsigned* Bu = (const unsigned*)&Bv;
      const unsigned* Cu = (const unsigned*)&C;
      const unsigned* Du = (const unsigned*)&D;
#pragma unroll
      for (int d = 0; d < 4; ++d) {
        unsigned acc = pk_mul_blo(Au[d], w0);
        acc = pk_fma_bhi(Bu[d], w0, acc);
        acc = pk_fma_blo(Cu[d], w1, acc);
        acc = pk_fma_bhi(Du[d], w1, acc);
        res[d] = acc;
      }
      *(uint4*)(&sV[(jl * 64 + px1) * 64 + slot]) =
          make_uint4(res[0], res[1], res[2], res[3]);
    }
    __syncthreads();                             // sV half ready

    // ---- phase E: main GEMM half ----
#pragma unroll 5
    for (int si = 0; si < sn; ++si) {
      int s = s0 + si;
      const short* aF = wtbF + (size_t)(s * 4 + wm) * 1024;
      half8 a0 = *(const half8*)(aF + afrag);
      half8 a1 = *(const half8*)(aF + 512 + afrag);
      int jl = (s >> 1) - j0;
      int oct = ((s & 1) * 4 + quad) ^ xkey;    // swizzled octet slot
      half8 bb0 = *(const half8*)(&sV[(jl * 64 + wn2 * 32 + l15) * 64 + oct * 8]);
      half8 bb1 = *(const half8*)(&sV[(jl * 64 + wn2 * 32 + 16 + l15) * 64 + oct * 8]);
      acc00 = __builtin_amdgcn_mfma_f32_16x16x32_f16(a0, bb0, acc00, 0, 0, 0);
      acc01 = __builtin_amdgcn_mfma_f32_16x16x32_f16(a0, bb1, acc01, 0, 0, 0);
      acc10 = __builtin_amdgcn_mfma_f32_16x16x32_f16(a1, bb0, acc10, 0, 0, 0);
      acc11 = __builtin_amdgcn_mfma_f32_16x16x32_f16(a1, bb1, acc11, 0, 0, 0);
    }
    if (half == 0) __syncthreads();              // E1 done reading before D2 writes
  }

  // ---- epilogue ----
  float* outb = out + (size_t)b * COUT * HW + hw0 + wn2 * 32;
#pragma unroll
  for (int r = 0; r < 4; ++r) {
    int o = wm * 32 + quad * 4 + r;
    float bo = bias[o];
    outb[(size_t)o * HW + l15]      = acc00[r] + bo;
    outb[(size_t)o * HW + 16 + l15] = acc01[r] + bo;
    int o1 = o + 16;
    float bo1 = bias[o1];
    outb[(size_t)o1 * HW + l15]      = acc10[r] + bo1;
    outb[(size_t)o1 * HW + 16 + l15] = acc11[r] + bo1;
  }
}

// ---------------------------------------------------------------------------
extern "C" void kernel_launch(void* const* d_in, const int* in_sizes, int n_in,
                              void* d_out, int out_size, void* d_ws, size_t ws_size,
                              hipStream_t stream) {
  const float* input_feat = (const float*)d_in[0];  // [4,64,128,128]
  const float* inter      = (const float*)d_in[1];  // [4,64,128,128]
  const float* weight     = (const float*)d_in[2];  // [128,64,3,3]
  const float* bias       = (const float*)d_in[3];  // [128]
  const float* w_om       = (const float*)d_in[4];  // [27,128,3,3]
  const float* b_om       = (const float*)d_in[5];  // [27]
  float* out = (float*)d_out;                       // [4,128,128,128]

  short* wtbF   = (short*)d_ws;                          // 147456 B
  short* wtbomF = (short*)((char*)d_ws + 147456);        // 73728 B
  short* xd     = (short*)((char*)d_ws + 221184);        // 8388608 B
  short* xi     = (short*)((char*)d_ws + 8609792);       // 8388608 B (~17 MB)

  k_tr<<<NB * (HW / 64), 256, 0, stream>>>(input_feat, inter, weight, w_om,
                                           xd, xi, wtbF, wtbomF);
  k_dcn<<<NB * (HW / 64), 512, 0, stream>>>(xd, xi, wtbF, wtbomF, b_om, bias, out);
}